// Round 4
// baseline (706.110 us; speedup 1.0000x reference)
//
#include <hip/hip_runtime.h>

// QuantizedLinear via int8 MFMA, 256x128-tile GEMM, K-slot-phased pipeline.
// out[M,N] = x[M,K] @ W[N,K]^T + bias; W int4 exact in i8, x per-row i8.
// BK=128 = one scale group; i32 accumulate per group (exact), drained to f32
// with group scale once per K-tile.
//
// R3 lesson: quadrant-cut phases (8 MFMA / 8 ds_read_b128 per wave) made the
// kernel LDS-read-bound: 64 KB LDS reads per phase per CU (~512-770 cyc) vs
// 326 cyc MFMA per SIMD -> MfmaUtil 26%, 224 us. i8 MFMA is 2x faster per
// byte than bf16, so phases must be cut along K-slots: phase = one K=64 slot
// over the wave's whole 64x64 tile = 16 MFMA / 8 ds_reads (A,B frags each
// read ONCE per tile). ci chains in i32 across the tile's 2 phases; one
// f32 drain per tile. Counted vmcnt (8/4/-/4), never 0 in loop.

typedef int i32x4 __attribute__((ext_vector_type(4)));

#define GAS __attribute__((address_space(1)))
#define LAS __attribute__((address_space(3)))

static constexpr int M_DIM = 8192;
static constexpr int N_DIM = 4096;
static constexpr int K_DIM = 4096;

// ---------------- x fp32 -> i8 per-row (one block per row of 4096) ----------------
__global__ __launch_bounds__(256) void quant_x(const float* __restrict__ x,
                                               signed char* __restrict__ xq,
                                               float* __restrict__ sx) {
    const int row = blockIdx.x;
    const int tid = threadIdx.x;
    const float* xr = x + (size_t)row * K_DIM;
    float4 v[4];
#pragma unroll
    for (int i = 0; i < 4; ++i) v[i] = *(const float4*)(xr + i * 1024 + tid * 4);
    float m = 0.f;
#pragma unroll
    for (int i = 0; i < 4; ++i)
        m = fmaxf(m, fmaxf(fmaxf(fabsf(v[i].x), fabsf(v[i].y)),
                           fmaxf(fabsf(v[i].z), fabsf(v[i].w))));
#pragma unroll
    for (int off = 32; off >= 1; off >>= 1) m = fmaxf(m, __shfl_xor(m, off, 64));
    __shared__ float wm[4];
    if ((tid & 63) == 0) wm[tid >> 6] = m;
    __syncthreads();
    m = fmaxf(fmaxf(wm[0], wm[1]), fmaxf(wm[2], wm[3]));
    const float inv = 127.f / m;
    if (tid == 0) sx[row] = m / 127.f;
#pragma unroll
    for (int i = 0; i < 4; ++i) {
        int b0 = (int)rintf(v[i].x * inv) & 255;
        int b1 = (int)rintf(v[i].y * inv) & 255;
        int b2 = (int)rintf(v[i].z * inv) & 255;
        int b3 = (int)rintf(v[i].w * inv) & 255;
        *(int*)(xq + (size_t)row * K_DIM + i * 1024 + tid * 4) =
            b0 | (b1 << 8) | (b2 << 16) | (b3 << 24);
    }
}

// ---------------- packed int4 -> raw i8 (values q-8 in [-8,7], NO scale) ----------------
__global__ __launch_bounds__(256) void unpack_w(const int* __restrict__ wp,
                                                signed char* __restrict__ wq) {
    const int t = blockIdx.x * 256 + threadIdx.x;   // 4 packed words -> 8 bytes out
    int4 p = *(const int4*)(wp + (size_t)t * 4);
    int pv[4] = {p.x, p.y, p.z, p.w};
    int w01 = (((pv[0] & 15) - 8) & 255) | (((((pv[0] >> 4) & 15) - 8) & 255) << 8) |
              ((((pv[1] & 15) - 8) & 255) << 16) | (((((pv[1] >> 4) & 15) - 8) & 255) << 24);
    int w23 = (((pv[2] & 15) - 8) & 255) | (((((pv[2] >> 4) & 15) - 8) & 255) << 8) |
              ((((pv[3] & 15) - 8) & 255) << 16) | (((((pv[3] >> 4) & 15) - 8) & 255) << 24);
    *(int2*)(wq + (size_t)t * 8) = make_int2(w01, w23);
}

// ---------------- scales [N][32] -> scalesT [32][N] (coalesced gemm reads) ----------------
__global__ __launch_bounds__(256) void transp_scales(const float* __restrict__ s,
                                                     float* __restrict__ st) {
    const int t = blockIdx.x * 256 + threadIdx.x;   // over 4096*32
    st[(size_t)(t & 31) * N_DIM + (t >> 5)] = s[t];
}

// ---------------- i8 GEMM, B^T, 256x128 tile, BK=128, K-slot phases ----------------
// 512 thr = 8 waves (4M x 2N); per-wave output 64x64 = 4x4 frags of 16x16.
// LDS 96 KiB: A [2buf][256 x 128 B] (64 KiB), B [2buf][128 x 128 B] (32 KiB @ +64 KiB).
// Row = 128 B = 8 chunks of 16 B; chunk c stored at slot c ^ (row&7).
// Iteration = 2 K-tiles: t0=2it (buf0, ph1=ks0 ph2=ks1), t1=2it+1 (buf1, ph3/ph4).
// Phase = all 16 MFMA of one K=64 slot; 4 A + 4 B ds_read_b128 per wave.
// ci[4][4] i32 chains ks0->ks1; drain to accf with group scale after ks1.
//
// Staging (per-thread issues): ph1: A(t1->buf1) 4; ph2: B(t1->buf1) 2 + SJ 4;
//                              ph3: A(t0+2->buf0) 4; ph4: B(t0+2->buf0) 2 + SJ 4.
// Ledger (guard = oldest load the NEXT phase needs):
//   end-ph1: guard B(t0) [prev ph4, before its SJ]; newer = ph4'SJ(4)+ph1(4) = 8 -> vmcnt(8)
//   end-ph2: guard B(t1) [this ph2];                newer = ph2 SJ(4)          -> vmcnt(4)
//   end-ph3: ph4 reads buf1 ks1, already guarded                              -> clobber only
//   end-ph4: guard B(t0+2) [this ph4];              newer = ph4 SJ(4)         -> vmcnt(4)
// Never vmcnt(0) in loop; max ~14 outstanding.

#define STAGE_A(BUF, TAU) do { \
  _Pragma("unroll") \
  for (int r_ = 0; r_ < 4; ++r_) { \
    const int rbase_ = (r_ * 8 + wv) * 8; \
    const int c_ = (l & 7) ^ (l >> 3); \
    const signed char* sA_ = Aq + (size_t)(m0 + rbase_ + (l >> 3)) * K_DIM \
                                + (size_t)(TAU) * 128 + c_ * 16; \
    __builtin_amdgcn_global_load_lds((const GAS void*)sA_, \
        (LAS void*)(lds + (BUF) * 32768 + rbase_ * 128), 16, 0, 0); \
  } \
} while (0)

#define STAGE_B(BUF, TAU) do { \
  _Pragma("unroll") \
  for (int r_ = 0; r_ < 2; ++r_) { \
    const int rbase_ = (r_ * 8 + wv) * 8; \
    const int c_ = (l & 7) ^ (l >> 3); \
    const signed char* sB_ = Bq + (size_t)(n0 + rbase_ + (l >> 3)) * K_DIM \
                                + (size_t)(TAU) * 128 + c_ * 16; \
    __builtin_amdgcn_global_load_lds((const GAS void*)sB_, \
        (LAS void*)(lds + 65536 + (BUF) * 16384 + rbase_ * 128), 16, 0, 0); \
  } \
} while (0)

#define LOAD_SJ(DST, G) do { \
  _Pragma("unroll") \
  for (int j_ = 0; j_ < 4; ++j_) \
    DST[j_] = scalesT[(size_t)(G) * N_DIM + n0 + wc * 64 + j_ * 16 + lr]; \
} while (0)

// One K=64 slot over the wave's 64x64 tile: 8 ds_read_b128 + 16 MFMA.
#define PHASE_MFMA(B, KS, INIT) do { \
  i32x4 aF_[4], bF_[4]; \
  _Pragma("unroll") \
  for (int nj = 0; nj < 4; ++nj) { \
    const int rb = wc * 64 + nj * 16 + lr; \
    bF_[nj] = *(const i32x4*)(lds + 65536 + (B) * 16384 + rb * 128 \
                              + ((((KS) * 4 + quad) ^ (rb & 7)) << 4)); \
  } \
  _Pragma("unroll") \
  for (int mi = 0; mi < 4; ++mi) { \
    const int ra = wr * 64 + mi * 16 + lr; \
    aF_[mi] = *(const i32x4*)(lds + (B) * 32768 + ra * 128 \
                              + ((((KS) * 4 + quad) ^ (ra & 7)) << 4)); \
  } \
  __builtin_amdgcn_s_setprio(1); \
  _Pragma("unroll") \
  for (int mi = 0; mi < 4; ++mi) \
    _Pragma("unroll") \
    for (int nj = 0; nj < 4; ++nj) \
      ci[mi][nj] = __builtin_amdgcn_mfma_i32_16x16x64_i8( \
          aF_[mi], bF_[nj], (INIT) ? izero : ci[mi][nj], 0, 0, 0); \
  __builtin_amdgcn_s_setprio(0); \
} while (0)

#define DRAIN(SJ) do { \
  _Pragma("unroll") \
  for (int mi = 0; mi < 4; ++mi) \
    _Pragma("unroll") \
    for (int nj = 0; nj < 4; ++nj) \
      _Pragma("unroll") \
      for (int r = 0; r < 4; ++r) \
        accf[mi][nj][r] += (SJ)[nj] * (float)ci[mi][nj][r]; \
} while (0)

#define VMW(N) asm volatile("s_waitcnt vmcnt(" #N ")" ::: "memory")
#define CLB()  asm volatile("" ::: "memory")
// Barrier + post-clobber so next phase's ds_reads cannot float above s_barrier
// into the window after this wave's vmcnt (cross-wave DMA completion needs BAR).
#define BAR()  do { __builtin_amdgcn_s_barrier(); asm volatile("" ::: "memory"); } while (0)

__global__ __launch_bounds__(512)
__attribute__((amdgpu_waves_per_eu(2, 2)))
void gemm_i8(const signed char* __restrict__ Aq,
             const signed char* __restrict__ Bq,
             const float* __restrict__ scalesT,
             const float* __restrict__ sx,
             const float* __restrict__ bias,
             float* __restrict__ C) {
    __shared__ signed char lds[98304];

    const int tid  = threadIdx.x;
    const int l    = tid & 63;
    const int wv   = tid >> 6;      // 0..7
    const int wr   = wv >> 1;       // 0..3  (M quarter of 256)
    const int wc   = wv & 1;        // 0..1  (N half of 128)
    const int lr   = l & 15;
    const int quad = l >> 4;

    // XCD-aware swizzle: 1024 wgs = 8 XCDs x 128; per-XCD 8x16 tile rect (bijective).
    const int bid = blockIdx.x;
    const int xcd = bid & 7, kk = bid >> 3;          // kk in [0,128)
    const int by = (xcd >> 1) * 8 + (kk & 7);        // m-tile 0..31 (256-row tiles)
    const int bx = (xcd & 1) * 16 + (kk >> 3);       // n-tile 0..31 (128-col tiles)
    const int m0 = by * 256, n0 = bx * 128;

    float accf[4][4][4];
#pragma unroll
    for (int i = 0; i < 4; ++i)
#pragma unroll
        for (int j = 0; j < 4; ++j)
#pragma unroll
            for (int r = 0; r < 4; ++r) accf[i][j][r] = 0.f;

    const i32x4 izero = {0, 0, 0, 0};
    float sjc0[4], sjc1[4], sjn0[4], sjn1[4];

    // Prologue: stage tile 0 -> buf0, then scales for tiles 0,1.
    // vmcnt(8) leaves the 8 SJ loads outstanding, guards A(0),B(0).
    STAGE_A(0, 0);
    STAGE_B(0, 0);
    LOAD_SJ(sjc0, 0);
    LOAD_SJ(sjc1, 1);
    VMW(8);
    BAR();

#pragma unroll 1
    for (int it = 0; it < 16; ++it) {
        const int t1  = it * 2 + 1;
        const int tn0 = (it * 2 + 2) & 31;
        const int tn1 = (it * 2 + 3) & 31;

        i32x4 ci[4][4];

        // ph1: tile t0 ks0
        STAGE_A(1, t1);
        PHASE_MFMA(0, 0, 1);
        VMW(8); BAR();

        // ph2: tile t0 ks1 (+drain t0)
        STAGE_B(1, t1);
        LOAD_SJ(sjn0, tn0);
        PHASE_MFMA(0, 1, 0);
        DRAIN(sjc0);
        VMW(4); BAR();

        // ph3: tile t1 ks0
        STAGE_A(0, tn0);
        PHASE_MFMA(1, 0, 1);
        CLB(); BAR();

        // ph4: tile t1 ks1 (+drain t1)
        STAGE_B(0, tn0);
        LOAD_SJ(sjn1, tn1);
        PHASE_MFMA(1, 1, 0);
        DRAIN(sjc1);
        VMW(4); BAR();

#pragma unroll
        for (int j = 0; j < 4; ++j) { sjc0[j] = sjn0[j]; sjc1[j] = sjn1[j]; }
    }

    // Drain leftover wrap-staged DMA before the block exits.
    asm volatile("s_waitcnt vmcnt(0)" ::: "memory");

    // Epilogue: C/D layout col=lane&15, row=quad*4+reg (verified, dtype-independent)
    float sxr[4][4];
#pragma unroll
    for (int i = 0; i < 4; ++i)
#pragma unroll
        for (int r = 0; r < 4; ++r)
            sxr[i][r] = sx[m0 + wr * 64 + i * 16 + quad * 4 + r];
#pragma unroll
    for (int j = 0; j < 4; ++j) {
        const int gn = n0 + wc * 64 + j * 16 + lr;
        const float bv = bias[gn];
#pragma unroll
        for (int i = 0; i < 4; ++i) {
            const size_t gm = (size_t)m0 + wr * 64 + i * 16 + quad * 4;
#pragma unroll
            for (int r = 0; r < 4; ++r)
                C[(gm + r) * N_DIM + gn] = accf[i][j][r] * sxr[i][r] + bv;
        }
    }
}

extern "C" void kernel_launch(void* const* d_in, const int* in_sizes, int n_in,
                              void* d_out, int out_size, void* d_ws, size_t ws_size,
                              hipStream_t stream) {
    const float* x      = (const float*)d_in[0];   // [4,2048,4096] fp32
    const int*   wp     = (const int*)d_in[1];     // [4096,2048] int32 (uint8 semantics)
    const float* scales = (const float*)d_in[2];   // [4096,32]
    const float* bias   = (const float*)d_in[4];   // [4096]
    float* out = (float*)d_out;

    signed char* Xq = (signed char*)d_ws;                                   // 32 MB
    signed char* Wq = (signed char*)d_ws + (size_t)M_DIM * K_DIM;           // +16 MB
    float* sx  = (float*)((char*)d_ws + (size_t)M_DIM * K_DIM + (size_t)N_DIM * K_DIM);          // +32 KB
    float* scT = (float*)((char*)d_ws + (size_t)M_DIM * K_DIM + (size_t)N_DIM * K_DIM + 32768);  // +512 KB

    quant_x<<<M_DIM, 256, 0, stream>>>(x, Xq, sx);
    unpack_w<<<(N_DIM * (K_DIM / 2) / 4) / 256, 256, 0, stream>>>(wp, Wq);
    transp_scales<<<(N_DIM * 32) / 256, 256, 0, stream>>>(scales, scT);
    gemm_i8<<<dim3(1024), 512, 0, stream>>>(Xq, Wq, scT, sx, bias, out);
}